// Round 3
// baseline (490.601 us; speedup 1.0000x reference)
//
#include <hip/hip_runtime.h>
#include <math.h>

#define BATCH 8
#define NN 2048
#define DIN 256
#define RANK 64
#define TOPKK 32
#define NCAND 40

static constexpr size_t A_ELEMS = (size_t)BATCH * NN * NN;   // 33554432
static constexpr size_t S_OFF   = A_ELEMS;
static constexpr size_t R_OFF   = 2 * A_ELEMS;
static constexpr size_t NROWS   = (size_t)BATCH * NN;        // 16384
// d_ws layout (float2 units): T2[NROWS][RANK] then R2[NROWS][RANK]  (16 MB total)
static constexpr size_t R2_OFF  = NROWS * RANK;

#define NEG_INF (-__builtin_inff())

// ---------------- threefry2x32, JAX partitionable counter-mode ----------------
// bits(i) = x0 ^ x1 of threefry2x32(key=(0,42), counter=(hi32(i), lo32(i)))
__device__ __forceinline__ unsigned rotl32(unsigned x, int d) {
  return (x << d) | (x >> (32 - d));
}

__device__ unsigned threefry_bits(unsigned flat) {
  const unsigned ks0 = 0u, ks1 = 42u, ks2 = 0u ^ 42u ^ 0x1BD11BDAu;
  unsigned x0 = 0u + ks0;        // hi32(flat) == 0 for our sizes
  unsigned x1 = flat + ks1;      // lo32(flat)
#define TF_ROUND(r) { x0 += x1; x1 = rotl32(x1, r); x1 ^= x0; }
  TF_ROUND(13) TF_ROUND(15) TF_ROUND(26) TF_ROUND(6)
  x0 += ks1; x1 += ks2 + 1u;
  TF_ROUND(17) TF_ROUND(29) TF_ROUND(16) TF_ROUND(24)
  x0 += ks2; x1 += ks0 + 2u;
  TF_ROUND(13) TF_ROUND(15) TF_ROUND(26) TF_ROUND(6)
  x0 += ks0; x1 += ks1 + 3u;
  TF_ROUND(17) TF_ROUND(29) TF_ROUND(16) TF_ROUND(24)
  x0 += ks1; x1 += ks2 + 4u;
  TF_ROUND(13) TF_ROUND(15) TF_ROUND(26) TF_ROUND(6)
  x0 += ks2; x1 += ks0 + 5u;
#undef TF_ROUND
  return x0 ^ x1;
}

__device__ __forceinline__ float2 split2(double v) {
  float hi = (float)v;
  float lo = (float)(v - (double)hi);
  return make_float2(hi, lo);
}

// ---------------- kernel 1: R = X*W ; T = (R*B)/8 — f64 accumulation ----------------
__global__ __launch_bounds__(256) void rt_kernel(const float* __restrict__ X,
                                                 const float* __restrict__ W,
                                                 const float* __restrict__ Bm,
                                                 float* __restrict__ out,
                                                 float2* __restrict__ ws) {
  __shared__ float  Xs[32][256];   // 32 KB
  __shared__ float  Bs[64][64];    // 16 KB
  __shared__ double Rs[32][64];    // 16 KB (f64 R for exact T)
  const int t = threadIdx.x;
  const int blk = blockIdx.x;     // 512 blocks
  const int b  = blk >> 6;        // batch
  const int rb = blk & 63;        // 32-row block
  const float* Xb = X + ((size_t)b * NN + (size_t)rb * 32) * DIN;

#pragma unroll
  for (int it = 0; it < 8; ++it) {
    int flat = it * 1024 + t * 4;
    float4 f = *(const float4*)(Xb + flat);
    *(float4*)&Xs[flat >> 8][flat & 255] = f;
  }
#pragma unroll
  for (int it = 0; it < 4; ++it) {
    int flat = it * 1024 + t * 4;
    float4 f = *(const float4*)(Bm + flat);
    *(float4*)&Bs[flat >> 6][flat & 63] = f;
  }
  __syncthreads();

  const int j = t & 63, rg = t >> 6;
  double acc[8] = {0, 0, 0, 0, 0, 0, 0, 0};
  for (int k = 0; k < DIN; k += 4) {
    double w0 = (double)W[(k + 0) * RANK + j];
    double w1 = (double)W[(k + 1) * RANK + j];
    double w2 = (double)W[(k + 2) * RANK + j];
    double w3 = (double)W[(k + 3) * RANK + j];
#pragma unroll
    for (int ii = 0; ii < 8; ++ii) {
      float4 xv = *(const float4*)&Xs[rg * 8 + ii][k];
      acc[ii] += (double)xv.x * w0 + (double)xv.y * w1 +
                 (double)xv.z * w2 + (double)xv.w * w3;
    }
  }
  const size_t grow0 = (size_t)b * NN + (size_t)rb * 32;
  float*  Rout = out + R_OFF + grow0 * RANK;
  float2* R2o  = ws + R2_OFF + grow0 * RANK;
#pragma unroll
  for (int ii = 0; ii < 8; ++ii) {
    int r = rg * 8 + ii;
    Rout[(size_t)r * RANK + j] = (float)acc[ii];
    R2o[(size_t)r * RANK + j]  = split2(acc[ii]);
    Rs[r][j] = acc[ii];
  }
  __syncthreads();

  double acc2[8] = {0, 0, 0, 0, 0, 0, 0, 0};
  for (int r = 0; r < RANK; ++r) {
    double bj = (double)Bs[r][j];
#pragma unroll
    for (int ii = 0; ii < 8; ++ii)
      acc2[ii] += Rs[rg * 8 + ii][r] * bj;   // broadcast LDS read, no conflict
  }
  // T scratch (f32) in the A output region (overwritten later by topk_kernel)
  float*  Tout = out + grow0 * RANK;
  float2* T2o  = ws + grow0 * RANK;
#pragma unroll
  for (int ii = 0; ii < 8; ++ii) {
    int r = rg * 8 + ii;
    double tv = acc2[ii] * 0.125;            // fold 1/sqrt(RANK), exact scaling
    Tout[(size_t)r * RANK + j] = (float)tv;
    T2o[(size_t)r * RANK + j]  = split2(tv);
  }
}

// ---------------- kernel 2: S = T * R^T (f32 output; selection refines in f64) ----------------
__global__ __launch_bounds__(256) void s_kernel(float* __restrict__ out) {
  __shared__ float Ts[64][68];
  __shared__ float Rs[64][68];
  const int t = threadIdx.x;
  const int bx = blockIdx.x;  // m tile (cols)
  const int by = blockIdx.y;  // n tile (rows)
  const int bz = blockIdx.z;  // batch
  const float* Tg = out + ((size_t)bz * NN + (size_t)by * 64) * RANK;
  const float* Rg = out + R_OFF + ((size_t)bz * NN + (size_t)bx * 64) * RANK;

#pragma unroll
  for (int it = 0; it < 4; ++it) {
    int flat = it * 1024 + t * 4;
    int r = flat >> 6, c = flat & 63;
    *(float4*)&Ts[r][c] = *(const float4*)(Tg + flat);
    *(float4*)&Rs[r][c] = *(const float4*)(Rg + flat);
  }
  __syncthreads();

  const int tx = t & 15, ty = t >> 4;
  float acc[4][4];
#pragma unroll
  for (int ii = 0; ii < 4; ++ii)
#pragma unroll
    for (int jj = 0; jj < 4; ++jj) acc[ii][jj] = 0.f;

  for (int k = 0; k < 64; k += 4) {
    float4 a[4], bb[4];
#pragma unroll
    for (int ii = 0; ii < 4; ++ii) a[ii] = *(const float4*)&Ts[ty + 16 * ii][k];
#pragma unroll
    for (int jj = 0; jj < 4; ++jj) bb[jj] = *(const float4*)&Rs[tx + 16 * jj][k];
#pragma unroll
    for (int ii = 0; ii < 4; ++ii)
#pragma unroll
      for (int jj = 0; jj < 4; ++jj)
        acc[ii][jj] += a[ii].x * bb[jj].x + a[ii].y * bb[jj].y +
                       a[ii].z * bb[jj].z + a[ii].w * bb[jj].w;
  }

  float* Sb = out + S_OFF + (size_t)bz * NN * NN;
#pragma unroll
  for (int ii = 0; ii < 4; ++ii) {
    int n = by * 64 + ty + 16 * ii;
#pragma unroll
    for (int jj = 0; jj < 4; ++jj) {
      int m = bx * 64 + tx + 16 * jj;
      Sb[(size_t)n * NN + m] = acc[ii][jj];
    }
  }
}

// ---------------- kernel 3: screen top-40 (f32) -> refine f64 -> top-32 -> softmax/dropout -> A ----------------
__global__ __launch_bounds__(256) void topk_kernel(const float* __restrict__ Sg,
                                                   float* __restrict__ A,
                                                   const float2* __restrict__ ws) {
  __shared__ float rowbuf[4][2048];  // 32 KB, one row per wave
  const int t = threadIdx.x;
  const int wv = t >> 6;
  const int lane = t & 63;
  const int wave = blockIdx.x * 4 + wv;    // global row id: b*2048 + n
  const int n = wave & (NN - 1);

  const float* row = Sg + (size_t)wave * NN;
  float v[32];
#pragma unroll
  for (int jj = 0; jj < 8; ++jj) {
    float4 f = *(const float4*)(row + jj * 256 + lane * 4);
    v[jj * 4 + 0] = f.x; v[jj * 4 + 1] = f.y;
    v[jj * 4 + 2] = f.z; v[jj * 4 + 3] = f.w;
  }
  unsigned alive = 0xFFFFFFFFu;
  {  // exclude diagonal: col(slot) = 256*(slot>>2) + 4*lane + (slot&3)
    int d = n - lane * 4;
    if (d >= 0 && d < NN && (d & 255) < 4)
      alive &= ~(1u << (((d >> 8) << 2) | (d & 3)));
  }

  // ---- screening: top-NCAND by f32 value (ties: lower col) ----
  float scv = NEG_INF; int scc = 0x7fffffff;
  for (int it = 0; it < NCAND; ++it) {
    float lm = NEG_INF; int li = 0;
#pragma unroll
    for (int jj = 0; jj < 32; ++jj) {
      float cand = ((alive >> jj) & 1u) ? v[jj] : NEG_INF;
      if (cand > lm) { lm = cand; li = jj; }
    }
    float bv = lm;
    int bi = ((li >> 2) << 8) + lane * 4 + (li & 3);
    if (!(bv > NEG_INF)) bi = 0x7fffffff;   // lane exhausted
#pragma unroll
    for (int off = 1; off < 64; off <<= 1) {
      float ov = __shfl_xor(bv, off, 64);
      int   oi = __shfl_xor(bi, off, 64);
      if (ov > bv || (ov == bv && oi < bi)) { bv = ov; bi = oi; }
    }
    if (lane == it) { scv = bv; scc = bi; }
    if (lane == ((bi >> 2) & 63))            // unique owner lane, integer-exact
      alive &= ~(1u << (((bi >> 8) << 2) | (bi & 3)));
  }
  (void)scv;

  // ---- f64 refinement of the NCAND candidates: S64[c] = sum_k T64[n][k]*R64[c][k] ----
  const int b = wave >> 11;
  float2 t2 = ws[(size_t)wave * RANK + lane];           // lane = k (RANK==64)
  double t64 = (double)t2.x + (double)t2.y;
  const float2* R2b = ws + R2_OFF + (size_t)b * NN * RANK;

  double fv = -__builtin_inf(); int fc = 0x7fffffff;
  for (int c = 0; c < NCAND; ++c) {
    int col = __shfl(scc, c, 64);
    float2 r2 = R2b[(size_t)col * RANK + lane];
    double p = t64 * ((double)r2.x + (double)r2.y);
#pragma unroll
    for (int off = 1; off < 64; off <<= 1) p += __shfl_xor(p, off, 64);
    if (lane == c) { fv = p; fc = col; }
  }

  // ---- final top-32 by f64 value (ties: lower col) ----
  double selv = -__builtin_inf(); int seli = 0;
  for (int it = 0; it < TOPKK; ++it) {
    double bv = fv; int bi = fc;
#pragma unroll
    for (int off = 1; off < 64; off <<= 1) {
      double ov = __shfl_xor(bv, off, 64);
      int    oi = __shfl_xor(bi, off, 64);
      if (ov > bv || (ov == bv && oi < bi)) { bv = ov; bi = oi; }
    }
    if (lane == it) { selv = bv; seli = bi; }
    if (fc == bi) { fv = -__builtin_inf(); fc = 0x7fffffff; }  // owner clears
  }

  // ---- softmax + dropout + renormalize, all f64 ----
  double m = __shfl(selv, 0, 64);
  double e = (lane < TOPKK) ? exp(selv - m) : 0.0;
  double s1 = e;
#pragma unroll
  for (int off = 1; off < 64; off <<= 1) s1 += __shfl_xor(s1, off, 64);
  double a1 = e / fmax(s1, 1e-6);

  double a2 = 0.0;
  if (lane < TOPKK) {
    unsigned flat = (unsigned)wave * 2048u + (unsigned)seli;
    unsigned bits = threefry_bits(flat);
    float u = __uint_as_float((bits >> 9) | 0x3f800000u) - 1.0f;
    u = fmaxf(u, 0.0f);
    if (u <= 0.9f) a2 = a1 / 0.9;
  }
  double s2 = a2;
#pragma unroll
  for (int off = 1; off < 64; off <<= 1) s2 += __shfl_xor(s2, off, 64);
  float av = (float)(a2 / fmax(s2, 1e-6));

  // materialize the full (mostly zero) row through LDS, then coalesced store
#pragma unroll
  for (int jj = 0; jj < 8; ++jj)
    *(float4*)&rowbuf[wv][jj * 256 + lane * 4] = make_float4(0.f, 0.f, 0.f, 0.f);
  __syncthreads();
  if (lane < TOPKK) rowbuf[wv][seli] = av;
  __syncthreads();
  float* Arow = A + (size_t)wave * NN;
#pragma unroll
  for (int jj = 0; jj < 8; ++jj)
    *(float4*)(Arow + jj * 256 + lane * 4) = *(float4*)&rowbuf[wv][jj * 256 + lane * 4];
}

extern "C" void kernel_launch(void* const* d_in, const int* in_sizes, int n_in,
                              void* d_out, int out_size, void* d_ws, size_t ws_size,
                              hipStream_t stream) {
  const float* X  = (const float*)d_in[0];
  const float* W  = (const float*)d_in[1];
  const float* Bm = (const float*)d_in[2];
  float* out = (float*)d_out;
  float2* ws = (float2*)d_ws;   // needs 16 MB: T2 (8 MB) + R2 (8 MB)

  hipLaunchKernelGGL(rt_kernel, dim3(512), dim3(256), 0, stream, X, W, Bm, out, ws);
  hipLaunchKernelGGL(s_kernel, dim3(32, 32, 8), dim3(256), 0, stream, out);
  hipLaunchKernelGGL(topk_kernel, dim3(4096), dim3(256), 0, stream, out + S_OFF, out, ws);
}

// Round 4
// 163.741 us; speedup vs baseline: 2.9962x; 2.9962x over previous
//
#include <hip/hip_runtime.h>
#include <math.h>

#define BATCH 8
#define NN 2048
#define DIN 256
#define RANK 64
#define TOPKK 32

static constexpr size_t A_ELEMS = (size_t)BATCH * NN * NN;   // 33554432
static constexpr size_t S_OFF   = A_ELEMS;
static constexpr size_t R_OFF   = 2 * A_ELEMS;

#define NEG_INF (-__builtin_inff())

// ---------------- threefry2x32, JAX partitionable counter-mode (verified r3) ----------------
__device__ __forceinline__ unsigned rotl32(unsigned x, int d) {
  return (x << d) | (x >> (32 - d));
}

__device__ unsigned threefry_bits(unsigned flat) {
  const unsigned ks0 = 0u, ks1 = 42u, ks2 = 0u ^ 42u ^ 0x1BD11BDAu;
  unsigned x0 = 0u + ks0;        // hi32(flat) == 0 for our sizes
  unsigned x1 = flat + ks1;      // lo32(flat)
#define TF_ROUND(r) { x0 += x1; x1 = rotl32(x1, r); x1 ^= x0; }
  TF_ROUND(13) TF_ROUND(15) TF_ROUND(26) TF_ROUND(6)
  x0 += ks1; x1 += ks2 + 1u;
  TF_ROUND(17) TF_ROUND(29) TF_ROUND(16) TF_ROUND(24)
  x0 += ks2; x1 += ks0 + 2u;
  TF_ROUND(13) TF_ROUND(15) TF_ROUND(26) TF_ROUND(6)
  x0 += ks0; x1 += ks1 + 3u;
  TF_ROUND(17) TF_ROUND(29) TF_ROUND(16) TF_ROUND(24)
  x0 += ks1; x1 += ks2 + 4u;
  TF_ROUND(13) TF_ROUND(15) TF_ROUND(26) TF_ROUND(6)
  x0 += ks2; x1 += ks0 + 5u;
#undef TF_ROUND
  return x0 ^ x1;
}

__device__ __forceinline__ unsigned long long make_key(float v, int col) {
  unsigned u = __float_as_uint(v);
  u = (u & 0x80000000u) ? ~u : (u | 0x80000000u);   // monotone order map
  return ((unsigned long long)u << 32) | (unsigned)(~col);  // ~col: equal vals -> lower col wins
}

// ---------------- kernel 1: R = X*W ; T = (R*B)/8 (f32) ----------------
__global__ __launch_bounds__(256) void rt_kernel(const float* __restrict__ X,
                                                 const float* __restrict__ W,
                                                 const float* __restrict__ Bm,
                                                 float* __restrict__ out) {
  __shared__ float Xs[32][256];   // 32 KB
  __shared__ float Bs[64][64];    // 16 KB
  __shared__ float Rs[32][64];    //  8 KB
  const int t = threadIdx.x;
  const int blk = blockIdx.x;     // 512 blocks
  const int b  = blk >> 6;
  const int rb = blk & 63;
  const float* Xb = X + ((size_t)b * NN + (size_t)rb * 32) * DIN;

#pragma unroll
  for (int it = 0; it < 8; ++it) {
    int flat = it * 1024 + t * 4;
    float4 f = *(const float4*)(Xb + flat);
    *(float4*)&Xs[flat >> 8][flat & 255] = f;
  }
#pragma unroll
  for (int it = 0; it < 4; ++it) {
    int flat = it * 1024 + t * 4;
    float4 f = *(const float4*)(Bm + flat);
    *(float4*)&Bs[flat >> 6][flat & 63] = f;
  }
  __syncthreads();

  const int j = t & 63, rg = t >> 6;
  float acc[8] = {0.f, 0.f, 0.f, 0.f, 0.f, 0.f, 0.f, 0.f};
  for (int k = 0; k < DIN; k += 4) {
    float w0 = W[(k + 0) * RANK + j];
    float w1 = W[(k + 1) * RANK + j];
    float w2 = W[(k + 2) * RANK + j];
    float w3 = W[(k + 3) * RANK + j];
#pragma unroll
    for (int ii = 0; ii < 8; ++ii) {
      float4 xv = *(const float4*)&Xs[rg * 8 + ii][k];
      acc[ii] += xv.x * w0 + xv.y * w1 + xv.z * w2 + xv.w * w3;
    }
  }
  const size_t grow0 = (size_t)b * NN + (size_t)rb * 32;
  float* Rout = out + R_OFF + grow0 * RANK;
#pragma unroll
  for (int ii = 0; ii < 8; ++ii) {
    Rout[(size_t)(rg * 8 + ii) * RANK + j] = acc[ii];
    Rs[rg * 8 + ii][j] = acc[ii];
  }
  __syncthreads();

  float acc2[8] = {0.f, 0.f, 0.f, 0.f, 0.f, 0.f, 0.f, 0.f};
  for (int r = 0; r < RANK; r += 4) {
    float b0 = Bs[r + 0][j];
    float b1 = Bs[r + 1][j];
    float b2 = Bs[r + 2][j];
    float b3 = Bs[r + 3][j];
#pragma unroll
    for (int ii = 0; ii < 8; ++ii) {
      float4 rv = *(const float4*)&Rs[rg * 8 + ii][r];
      acc2[ii] += rv.x * b0 + rv.y * b1 + rv.z * b2 + rv.w * b3;
    }
  }
  // T scratch lives in the A output region (overwritten later by topk_kernel)
  float* Tout = out + grow0 * RANK;
#pragma unroll
  for (int ii = 0; ii < 8; ++ii)
    Tout[(size_t)(rg * 8 + ii) * RANK + j] = acc2[ii] * 0.125f;  // fold 1/sqrt(RANK)
}

// ---------------- kernel 2: S = T * R^T ----------------
__global__ __launch_bounds__(256) void s_kernel(float* __restrict__ out) {
  __shared__ float Ts[64][68];
  __shared__ float Rs[64][68];
  const int t = threadIdx.x;
  const int bx = blockIdx.x;  // m tile (cols)
  const int by = blockIdx.y;  // n tile (rows)
  const int bz = blockIdx.z;  // batch
  const float* Tg = out + ((size_t)bz * NN + (size_t)by * 64) * RANK;
  const float* Rg = out + R_OFF + ((size_t)bz * NN + (size_t)bx * 64) * RANK;

#pragma unroll
  for (int it = 0; it < 4; ++it) {
    int flat = it * 1024 + t * 4;
    int r = flat >> 6, c = flat & 63;
    *(float4*)&Ts[r][c] = *(const float4*)(Tg + flat);
    *(float4*)&Rs[r][c] = *(const float4*)(Rg + flat);
  }
  __syncthreads();

  const int tx = t & 15, ty = t >> 4;
  float acc[4][4];
#pragma unroll
  for (int ii = 0; ii < 4; ++ii)
#pragma unroll
    for (int jj = 0; jj < 4; ++jj) acc[ii][jj] = 0.f;

  for (int k = 0; k < 64; k += 4) {
    float4 a[4], bb[4];
#pragma unroll
    for (int ii = 0; ii < 4; ++ii) a[ii] = *(const float4*)&Ts[ty + 16 * ii][k];
#pragma unroll
    for (int jj = 0; jj < 4; ++jj) bb[jj] = *(const float4*)&Rs[tx + 16 * jj][k];
#pragma unroll
    for (int ii = 0; ii < 4; ++ii)
#pragma unroll
      for (int jj = 0; jj < 4; ++jj)
        acc[ii][jj] += a[ii].x * bb[jj].x + a[ii].y * bb[jj].y +
                       a[ii].z * bb[jj].z + a[ii].w * bb[jj].w;
  }

  float* Sb = out + S_OFF + (size_t)bz * NN * NN;
#pragma unroll
  for (int ii = 0; ii < 4; ++ii) {
    int n = by * 64 + ty + 16 * ii;
#pragma unroll
    for (int jj = 0; jj < 4; ++jj) {
      int m = bx * 64 + tx + 16 * jj;
      Sb[(size_t)n * NN + m] = acc[ii][jj];
    }
  }
}

// ---------------- kernel 3: threshold-screen -> compact -> bitonic top-32 -> softmax/dropout -> A ----------------
__global__ __launch_bounds__(64) void topk_kernel(const float* __restrict__ Sg,
                                                  float* __restrict__ A) {
  __shared__ float rowbuf[NN];               // 8 KB
  __shared__ unsigned long long keys[64];    // 512 B
  __shared__ int cnt;
  const int lane = threadIdx.x;
  const int wave = blockIdx.x;               // global row id: b*2048 + n
  const int n = wave & (NN - 1);

  const float* row = Sg + (size_t)wave * NN;
  float v[32];
#pragma unroll
  for (int jj = 0; jj < 8; ++jj) {
    float4 f = *(const float4*)(row + jj * 256 + lane * 4);
    v[jj * 4 + 0] = f.x; v[jj * 4 + 1] = f.y;
    v[jj * 4 + 2] = f.z; v[jj * 4 + 3] = f.w;
  }

  // row stats (includes diag; 1/2048 bias irrelevant for a warm start)
  float s = 0.f, ss = 0.f;
#pragma unroll
  for (int jj = 0; jj < 32; ++jj) { s += v[jj]; ss = fmaf(v[jj], v[jj], ss); }
#pragma unroll
  for (int off = 1; off < 64; off <<= 1) {
    s  += __shfl_xor(s, off, 64);
    ss += __shfl_xor(ss, off, 64);
  }
  const float mu = s * (1.f / 2048.f);
  const float sigma = sqrtf(fmaxf(ss * (1.f / 2048.f) - mu * mu, 1e-12f));

  // exclude diagonal: slot for col c is ((c>>8)<<2)|(c&3) on lane (c>>2)&63
  {
    int d = n - lane * 4;
    if (d >= 0 && d < NN && (d & 255) < 4)
      v[((d >> 8) << 2) | (d & 3)] = NEG_INF;
  }

  // ---- threshold search: want count(v > tau) in [32, 64] ----
  float tau = mu + 2.0641f * sigma;          // Phi^-1(1 - 40/2048)
  float lo_b = -3.0e38f, hi_b = 3.0e38f;     // lo: count>64, hi: count<32
  float step = sigma + 1e-20f;
  bool found = false;
  for (int it = 0; it < 40; ++it) {
    int cl = 0;
#pragma unroll
    for (int jj = 0; jj < 32; ++jj) cl += (v[jj] > tau) ? 1 : 0;
#pragma unroll
    for (int off = 1; off < 64; off <<= 1) cl += __shfl_xor(cl, off, 64);
    if (cl >= TOPKK && cl <= 64) { found = true; break; }
    if (cl > 64) lo_b = fmaxf(lo_b, tau); else hi_b = fminf(hi_b, tau);
    float tn = 0.f; bool ok = false;
    if (it < 6) {  // Gaussian-model recalibration (Hastings inverse-normal)
      float p = fminf(fmaxf((float)cl, 1.f) * (1.f / 2048.f), 0.5f);
      float tt = sqrtf(-2.f * logf(p));
      float zc = tt - (2.30753f + 0.27061f * tt) /
                      (1.f + tt * (0.99229f + 0.04481f * tt));
      zc = fmaxf(zc, 0.05f);
      tn = mu + 2.0641f * ((tau - mu) / zc);
      ok = (tn > lo_b && tn < hi_b);         // NaN fails -> ok=false
    }
    if (!ok) {
      if (lo_b > -1.0e38f && hi_b < 1.0e38f) tn = 0.5f * lo_b + 0.5f * hi_b;
      else if (cl > 64) { tn = tau + step; step *= 2.f; }
      else             { tn = tau - step; step *= 2.f; }
    }
    tau = tn;
  }

  if (lane == 0) cnt = 0;
  __syncthreads();

  if (found) {
    // ---- compact candidates (order irrelevant; sort below is total) ----
#pragma unroll
    for (int jj = 0; jj < 32; ++jj) {
      if (v[jj] > tau) {
        int col = ((jj >> 2) << 8) + lane * 4 + (jj & 3);
        int pos = atomicAdd(&cnt, 1);
        if (pos < 64) keys[pos] = make_key(v[jj], col);
      }
    }
  } else {
    // ---- exact serial fallback (measure-zero path; correctness insurance) ----
    unsigned alive = 0xFFFFFFFFu;
    if (lane == 0) cnt = TOPKK;
    for (int it = 0; it < TOPKK; ++it) {
      unsigned long long best = 0ull;
#pragma unroll
      for (int jj = 0; jj < 32; ++jj) {
        if ((alive >> jj) & 1u) {
          int col = ((jj >> 2) << 8) + lane * 4 + (jj & 3);
          unsigned long long k = make_key(v[jj], col);
          if (k > best) best = k;
        }
      }
      unsigned long long b2 = best;
#pragma unroll
      for (int off = 1; off < 64; off <<= 1) {
        unsigned long long o = __shfl_xor(b2, off, 64);
        if (o > b2) b2 = o;
      }
      if (lane == 0) keys[it] = b2;
      if (best == b2) {   // unique owner (cols unique) clears its slot
#pragma unroll
        for (int jj = 0; jj < 32; ++jj) {
          int col = ((jj >> 2) << 8) + lane * 4 + (jj & 3);
          if (make_key(v[jj], col) == b2) alive &= ~(1u << jj);
        }
      }
    }
  }
  __syncthreads();

  const int cn = min(cnt, 64);
  unsigned long long key = (lane < cn) ? keys[lane] : 0ull;

  // ---- 64-lane bitonic sort, descending (lane 0 = max; ties -> lower col) ----
#pragma unroll
  for (int k = 2; k <= 64; k <<= 1) {
#pragma unroll
    for (int j = k >> 1; j >= 1; j >>= 1) {
      unsigned long long o = __shfl_xor(key, j, 64);
      bool lower = (lane & j) == 0;
      bool desc  = (lane & k) == 0;
      bool takeMax = (lower == desc);
      bool kgo = key > o;
      key = (takeMax == kgo) ? key : o;
    }
  }

  float val; int col;
  {
    unsigned hi = (unsigned)(key >> 32);
    unsigned ub = (hi & 0x80000000u) ? (hi ^ 0x80000000u) : ~hi;
    val = __uint_as_float(ub);
    col = (int)(~(unsigned)key) & (NN - 1);
  }

  // ---- softmax over selected (denominators cancel vs full-row softmax) ----
  float m = __shfl(val, 0, 64);
  float e = (lane < TOPKK) ? expf(val - m) : 0.f;
  float s1 = e;
#pragma unroll
  for (int off = 1; off < 64; off <<= 1) s1 += __shfl_xor(s1, off, 64);
  float a1 = e / fmaxf(s1, 1e-6f);

  // ---- dropout (threefry counter-mode) + renormalize ----
  float a2 = 0.f;
  if (lane < TOPKK) {
    unsigned flat = (unsigned)wave * 2048u + (unsigned)col;
    unsigned bits = threefry_bits(flat);
    float u = __uint_as_float((bits >> 9) | 0x3f800000u) - 1.0f;
    if (u <= 0.9f) a2 = a1 * (1.f / 0.9f);
  }
  float s2 = a2;
#pragma unroll
  for (int off = 1; off < 64; off <<= 1) s2 += __shfl_xor(s2, off, 64);
  float av = a2 / fmaxf(s2, 1e-6f);

  // ---- materialize row: zero LDS, scatter 32, coalesced store ----
#pragma unroll
  for (int jj = 0; jj < 8; ++jj)
    *(float4*)&rowbuf[jj * 256 + lane * 4] = make_float4(0.f, 0.f, 0.f, 0.f);
  __syncthreads();
  if (lane < TOPKK) rowbuf[col] = av;
  __syncthreads();
  float* Arow = A + (size_t)wave * NN;
#pragma unroll
  for (int jj = 0; jj < 8; ++jj)
    *(float4*)(Arow + jj * 256 + lane * 4) = *(float4*)&rowbuf[jj * 256 + lane * 4];
}

extern "C" void kernel_launch(void* const* d_in, const int* in_sizes, int n_in,
                              void* d_out, int out_size, void* d_ws, size_t ws_size,
                              hipStream_t stream) {
  const float* X  = (const float*)d_in[0];
  const float* W  = (const float*)d_in[1];
  const float* Bm = (const float*)d_in[2];
  float* out = (float*)d_out;

  hipLaunchKernelGGL(rt_kernel, dim3(512), dim3(256), 0, stream, X, W, Bm, out);
  hipLaunchKernelGGL(s_kernel, dim3(32, 32, 8), dim3(256), 0, stream, out);
  hipLaunchKernelGGL(topk_kernel, dim3(16384), dim3(64), 0, stream, out + S_OFF, out);
}